// Round 3
// baseline (184.481 us; speedup 1.0000x reference)
//
#include <hip/hip_runtime.h>

// Problem constants: B=32, H=512, W=512, P=100000
#define W_ 512
#define HWIMG (512 * 512)
#define P_ 100000
#define NTOT 3200000          // B*P
#define PTS 8                 // points per thread; P%8==0 so no batch straddle
#define BLOCK 320             // 5 waves
#define NBLK 1250             // 1250*320*8 == 3,200,000 exact

typedef int iv4 __attribute__((ext_vector_type(4)));   // clang vector: nontemporal-ok

__global__ void rdl_zero_kernel(float* out) {
    if (threadIdx.x == 0) out[0] = 0.0f;
}

__global__ __launch_bounds__(BLOCK, 4) void rdl_kernel(
    const float* __restrict__ img,
    const int*  __restrict__ xA, const int* __restrict__ yA,
    const int*  __restrict__ xB, const int* __restrict__ yB,
    const int*  __restrict__ ordn,
    float* __restrict__ out)
{
    const int t = blockIdx.x * BLOCK + threadIdx.x;       // 0 .. 400000-1 exact
    const int g = 2 * t;                                  // iv4-group index

    // ---- phase 1: stream indices (nontemporal: read-once, keep L2 for image)
    const iv4* xa_v = reinterpret_cast<const iv4*>(xA);
    const iv4* ya_v = reinterpret_cast<const iv4*>(yA);
    const iv4* xb_v = reinterpret_cast<const iv4*>(xB);
    const iv4* yb_v = reinterpret_cast<const iv4*>(yB);
    const iv4* od_v = reinterpret_cast<const iv4*>(ordn);

    iv4 xa0 = __builtin_nontemporal_load(xa_v + g);
    iv4 xa1 = __builtin_nontemporal_load(xa_v + g + 1);
    iv4 ya0 = __builtin_nontemporal_load(ya_v + g);
    iv4 ya1 = __builtin_nontemporal_load(ya_v + g + 1);
    iv4 xb0 = __builtin_nontemporal_load(xb_v + g);
    iv4 xb1 = __builtin_nontemporal_load(xb_v + g + 1);
    iv4 yb0 = __builtin_nontemporal_load(yb_v + g);
    iv4 yb1 = __builtin_nontemporal_load(yb_v + g + 1);
    iv4 od0 = __builtin_nontemporal_load(od_v + g);
    iv4 od1 = __builtin_nontemporal_load(od_v + g + 1);

    const int xa[PTS] = {xa0.x, xa0.y, xa0.z, xa0.w, xa1.x, xa1.y, xa1.z, xa1.w};
    const int ya[PTS] = {ya0.x, ya0.y, ya0.z, ya0.w, ya1.x, ya1.y, ya1.z, ya1.w};
    const int xb[PTS] = {xb0.x, xb0.y, xb0.z, xb0.w, xb1.x, xb1.y, xb1.z, xb1.w};
    const int yb[PTS] = {yb0.x, yb0.y, yb0.z, yb0.w, yb1.x, yb1.y, yb1.z, yb1.w};
    const int od[PTS] = {od0.x, od0.y, od0.z, od0.w, od1.x, od1.y, od1.z, od1.w};

    // batch index: 8 consecutive points, P%8==0 -> single batch per thread
    const int b = t / (P_ / PTS);                          // t / 12500
    const float* imb = img + (size_t)b * HWIMG;

    // ---- phase 2: issue all 16 gathers before any math (MLP)
    float zA[PTS], zB[PTS];
#pragma unroll
    for (int j = 0; j < PTS; ++j) zA[j] = imb[ya[j] * W_ + xa[j]];
#pragma unroll
    for (int j = 0; j < PTS; ++j) zB[j] = imb[yb[j] * W_ + xb[j]];

    // ---- phase 3: math
    float acc = 0.0f;
#pragma unroll
    for (int j = 0; j < PTS; ++j) {
        const float d  = zA[j] - zB[j];
        const float gt = (float)(od[j] - 1);               // in {-1, 0, 1}
        const float tt = -gt * d;
        // stable softplus: log1p(exp(tt)) = max(tt,0) + log1p(exp(-|tt|))
        const float sp = fmaxf(tt, 0.0f) + log1pf(expf(-fabsf(tt)));
        acc += (od[j] != 1) ? sp : d * d;
    }

    // ---- wave-64 shuffle reduction
#pragma unroll
    for (int off = 32; off > 0; off >>= 1)
        acc += __shfl_down(acc, off, 64);

    __shared__ float ws[BLOCK / 64];
    const int lane = threadIdx.x & 63;
    const int wid  = threadIdx.x >> 6;
    if (lane == 0) ws[wid] = acc;
    __syncthreads();
    if (threadIdx.x == 0) {
        float s = 0.0f;
#pragma unroll
        for (int w = 0; w < BLOCK / 64; ++w) s += ws[w];
        atomicAdd(out, s * (1.0f / (float)NTOT));
    }
}

extern "C" void kernel_launch(void* const* d_in, const int* in_sizes, int n_in,
                              void* d_out, int out_size, void* d_ws, size_t ws_size,
                              hipStream_t stream) {
    const float* img = (const float*)d_in[0];
    const int*   xA  = (const int*)d_in[1];
    const int*   yA  = (const int*)d_in[2];
    const int*   xB  = (const int*)d_in[3];
    const int*   yB  = (const int*)d_in[4];
    const int*   od  = (const int*)d_in[5];
    float* out = (float*)d_out;

    rdl_zero_kernel<<<1, 64, 0, stream>>>(out);
    rdl_kernel<<<NBLK, BLOCK, 0, stream>>>(img, xA, yA, xB, yB, od, out);
}

// Round 4
// 157.247 us; speedup vs baseline: 1.1732x; 1.1732x over previous
//
#include <hip/hip_runtime.h>
#include <stdint.h>

// Problem constants: B=32, H=512, W=512, P=100000
#define W_ 512
#define HWIMG (512 * 512)
#define P_ 100000
#define NTOT 3200000
#define PTS 8                  // points per thread (P%8==0)
#define BLOCK 320              // 5 waves
#define PPB (BLOCK * PTS)      // 2560 points per block
#define BPB 40                 // blocks per batch, padded: 40*2560 = 102400 >= 100000
#define NBLK (32 * BPB)        // 1280 blocks; entire grid resident (5/CU)

typedef int iv4 __attribute__((ext_vector_type(4)));

// Volatile-asm loads: the compiler cannot serialize these with its own
// waitcnt insertion; WE control when the wave waits.
__device__ __forceinline__ iv4 ldg_idx4_nt(const int* p) {
    iv4 r;
    asm volatile("global_load_dwordx4 %0, %1, off nt" : "=v"(r) : "v"(p));
    return r;
}
__device__ __forceinline__ float gather_f32(const float* p) {
    float r;
    asm volatile("global_load_dword %0, %1, off" : "=v"(r) : "v"(p));
    return r;
}

__global__ __launch_bounds__(BLOCK) void rdl_kernel(
    const float* __restrict__ img,
    const int*  __restrict__ xA, const int* __restrict__ yA,
    const int*  __restrict__ xB, const int* __restrict__ yB,
    const int*  __restrict__ ordn,
    float* __restrict__ out)
{
    // XCD-aware swizzle: blockIdx%8 ~ XCD (round-robin dispatch heuristic).
    // Each XCD owns 4 whole batches -> 4 MB of image slices == its L2.
    const int xcd   = blockIdx.x & 7;
    const int slot  = blockIdx.x >> 3;            // 0..159
    const int b     = xcd * 4 + slot / BPB;       // batch 0..31
    const int inner = slot % BPB;                 // 0..39
    const int base  = inner * PPB + threadIdx.x * PTS;   // point within batch

    float acc = 0.0f;
    if (base < P_) {                               // tail guard (padded grid)
        const int gi = b * P_ + base;              // flat (B,P) element index
        const float* imb = img + (size_t)b * HWIMG;

        // ---- phase 1: 10 index loads, all in flight, then ONE wait
        iv4 xa0 = ldg_idx4_nt(xA + gi); iv4 xa1 = ldg_idx4_nt(xA + gi + 4);
        iv4 ya0 = ldg_idx4_nt(yA + gi); iv4 ya1 = ldg_idx4_nt(yA + gi + 4);
        iv4 xb0 = ldg_idx4_nt(xB + gi); iv4 xb1 = ldg_idx4_nt(xB + gi + 4);
        iv4 yb0 = ldg_idx4_nt(yB + gi); iv4 yb1 = ldg_idx4_nt(yB + gi + 4);
        iv4 od0 = ldg_idx4_nt(ordn + gi); iv4 od1 = ldg_idx4_nt(ordn + gi + 4);
        asm volatile("s_waitcnt vmcnt(0)"
            : "+v"(xa0), "+v"(xa1), "+v"(ya0), "+v"(ya1),
              "+v"(xb0), "+v"(xb1), "+v"(yb0), "+v"(yb1),
              "+v"(od0), "+v"(od1));

        const int xa[PTS] = {xa0.x, xa0.y, xa0.z, xa0.w, xa1.x, xa1.y, xa1.z, xa1.w};
        const int ya[PTS] = {ya0.x, ya0.y, ya0.z, ya0.w, ya1.x, ya1.y, ya1.z, ya1.w};
        const int xb[PTS] = {xb0.x, xb0.y, xb0.z, xb0.w, xb1.x, xb1.y, xb1.z, xb1.w};
        const int yb[PTS] = {yb0.x, yb0.y, yb0.z, yb0.w, yb1.x, yb1.y, yb1.z, yb1.w};
        const int od[PTS] = {od0.x, od0.y, od0.z, od0.w, od1.x, od1.y, od1.z, od1.w};

        // ---- phase 2: 16 gathers, all in flight, then ONE wait
        float zA[PTS], zB[PTS];
#pragma unroll
        for (int j = 0; j < PTS; ++j) zA[j] = gather_f32(imb + (ya[j] << 9) + xa[j]);
#pragma unroll
        for (int j = 0; j < PTS; ++j) zB[j] = gather_f32(imb + (yb[j] << 9) + xb[j]);
        asm volatile("s_waitcnt vmcnt(0)"
            : "+v"(zA[0]), "+v"(zA[1]), "+v"(zA[2]), "+v"(zA[3]),
              "+v"(zA[4]), "+v"(zA[5]), "+v"(zA[6]), "+v"(zA[7]),
              "+v"(zB[0]), "+v"(zB[1]), "+v"(zB[2]), "+v"(zB[3]),
              "+v"(zB[4]), "+v"(zB[5]), "+v"(zB[6]), "+v"(zB[7]));

        // ---- phase 3: math
#pragma unroll
        for (int j = 0; j < PTS; ++j) {
            const float d  = zA[j] - zB[j];
            const float gt = (float)(od[j] - 1);            // {-1,0,1}
            const float tt = -gt * d;
            const float sp = fmaxf(tt, 0.0f) + log1pf(expf(-fabsf(tt)));
            acc += (od[j] != 1) ? sp : d * d;
        }
    }

    // ---- wave-64 shuffle reduction -> LDS -> one atomic per block
#pragma unroll
    for (int off = 32; off > 0; off >>= 1)
        acc += __shfl_down(acc, off, 64);

    __shared__ float ws[BLOCK / 64];
    const int lane = threadIdx.x & 63;
    const int wid  = threadIdx.x >> 6;
    if (lane == 0) ws[wid] = acc;
    __syncthreads();
    if (threadIdx.x == 0) {
        float s = 0.0f;
#pragma unroll
        for (int w = 0; w < BLOCK / 64; ++w) s += ws[w];
        atomicAdd(out, s * (1.0f / (float)NTOT));
    }
}

extern "C" void kernel_launch(void* const* d_in, const int* in_sizes, int n_in,
                              void* d_out, int out_size, void* d_ws, size_t ws_size,
                              hipStream_t stream) {
    const float* img = (const float*)d_in[0];
    const int*   xA  = (const int*)d_in[1];
    const int*   yA  = (const int*)d_in[2];
    const int*   xB  = (const int*)d_in[3];
    const int*   yB  = (const int*)d_in[4];
    const int*   od  = (const int*)d_in[5];
    float* out = (float*)d_out;

    hipMemsetAsync(out, 0, sizeof(float), stream);   // graph-capturable zero-init
    rdl_kernel<<<NBLK, BLOCK, 0, stream>>>(img, xA, yA, xB, yB, od, out);
}

// Round 5
// 152.698 us; speedup vs baseline: 1.2081x; 1.0298x over previous
//
#include <hip/hip_runtime.h>
#include <stdint.h>

// Problem constants: B=32, H=512, W=512, P=100000
#define W_ 512
#define HWIMG (512 * 512)
#define P_ 100000
#define NTOT 3200000
#define PTS 8                  // points per thread (P%8==0 -> all-or-nothing guard)
#define BLOCK 256              // 4 waves
#define PPB (BLOCK * PTS)      // 2048 points per block
#define BPB 49                 // blocks per batch: 49*2048 = 100352 >= 100000
#define NBLK (32 * BPB)        // 1568 blocks (~6.1 per CU)

typedef int iv4 __attribute__((ext_vector_type(4)));

// Volatile-asm loads: compiler cannot inject serializing waitcnts between
// these; WE decide when the wave waits.
__device__ __forceinline__ iv4 ldg_idx4_nt(const int* p) {
    iv4 r;
    asm volatile("global_load_dwordx4 %0, %1, off nt" : "=v"(r) : "v"(p));
    return r;
}
__device__ __forceinline__ float gather_f32(const float* p) {
    float r;
    asm volatile("global_load_dword %0, %1, off" : "=v"(r) : "v"(p));
    return r;
}

__global__ __launch_bounds__(BLOCK) void rdl_kernel(
    const float* __restrict__ img,
    const int*  __restrict__ xA, const int* __restrict__ yA,
    const int*  __restrict__ xB, const int* __restrict__ yB,
    const int*  __restrict__ ordn,
    float* __restrict__ out)
{
    // XCD swizzle: blockIdx%8 ~ XCD; each XCD owns 4 batches -> 4 MB image == its L2.
    const int xcd   = blockIdx.x & 7;
    const int slot  = blockIdx.x >> 3;            // 0..195
    const int b     = xcd * 4 + slot / BPB;       // batch 0..31
    const int inner = slot % BPB;                 // 0..48
    const int base  = inner * PPB + (threadIdx.x << 3);  // point within batch

    float acc = 0.0f;
    if (base < P_) {                               // all-or-nothing (base%8==0, P%8==0)
        const int gi = b * P_ + base;
        const float* imb = img + (size_t)b * HWIMG;

        // ---- phase 1: 10 coalesced index loads in flight, ONE wait
        iv4 xa0 = ldg_idx4_nt(xA + gi);   iv4 xa1 = ldg_idx4_nt(xA + gi + 4);
        iv4 ya0 = ldg_idx4_nt(yA + gi);   iv4 ya1 = ldg_idx4_nt(yA + gi + 4);
        iv4 xb0 = ldg_idx4_nt(xB + gi);   iv4 xb1 = ldg_idx4_nt(xB + gi + 4);
        iv4 yb0 = ldg_idx4_nt(yB + gi);   iv4 yb1 = ldg_idx4_nt(yB + gi + 4);
        iv4 od0 = ldg_idx4_nt(ordn + gi); iv4 od1 = ldg_idx4_nt(ordn + gi + 4);
        asm volatile("s_waitcnt vmcnt(0)"
            : "+v"(xa0), "+v"(xa1), "+v"(ya0), "+v"(ya1),
              "+v"(xb0), "+v"(xb1), "+v"(yb0), "+v"(yb1),
              "+v"(od0), "+v"(od1));

        const int xa[PTS] = {xa0.x, xa0.y, xa0.z, xa0.w, xa1.x, xa1.y, xa1.z, xa1.w};
        const int ya[PTS] = {ya0.x, ya0.y, ya0.z, ya0.w, ya1.x, ya1.y, ya1.z, ya1.w};
        const int xb[PTS] = {xb0.x, xb0.y, xb0.z, xb0.w, xb1.x, xb1.y, xb1.z, xb1.w};
        const int yb[PTS] = {yb0.x, yb0.y, yb0.z, yb0.w, yb1.x, yb1.y, yb1.z, yb1.w};
        const int od[PTS] = {od0.x, od0.y, od0.z, od0.w, od1.x, od1.y, od1.z, od1.w};

        // ---- phase 2: 16 gathers in flight, ONE wait
        float zA[PTS], zB[PTS];
#pragma unroll
        for (int j = 0; j < PTS; ++j) zA[j] = gather_f32(imb + (ya[j] << 9) + xa[j]);
#pragma unroll
        for (int j = 0; j < PTS; ++j) zB[j] = gather_f32(imb + (yb[j] << 9) + xb[j]);
        asm volatile("s_waitcnt vmcnt(0)"
            : "+v"(zA[0]), "+v"(zA[1]), "+v"(zA[2]), "+v"(zA[3]),
              "+v"(zA[4]), "+v"(zA[5]), "+v"(zA[6]), "+v"(zA[7]),
              "+v"(zB[0]), "+v"(zB[1]), "+v"(zB[2]), "+v"(zB[3]),
              "+v"(zB[4]), "+v"(zB[5]), "+v"(zB[6]), "+v"(zB[7]));

        // ---- phase 3: math with HW transcendentals (v_exp_f32 / v_log_f32).
        // softplus(t) = max(t,0) + log(1 + exp(-|t|)); per-term err < 1e-6,
        // mean-over-3.2M threshold is 2.5e-2 -> huge slack.
#pragma unroll
        for (int j = 0; j < PTS; ++j) {
            const float d  = zA[j] - zB[j];
            const float gt = (float)(od[j] - 1);            // {-1,0,1}
            const float tt = -gt * d;
            const float sp = fmaxf(tt, 0.0f) + __logf(1.0f + __expf(-fabsf(tt)));
            acc += (od[j] != 1) ? sp : d * d;
        }
    }

    // ---- wave-64 shuffle reduction -> LDS -> one atomic per block
#pragma unroll
    for (int off = 32; off > 0; off >>= 1)
        acc += __shfl_down(acc, off, 64);

    __shared__ float ws[BLOCK / 64];
    const int lane = threadIdx.x & 63;
    const int wid  = threadIdx.x >> 6;
    if (lane == 0) ws[wid] = acc;
    __syncthreads();
    if (threadIdx.x == 0) {
        float s = 0.0f;
#pragma unroll
        for (int w = 0; w < BLOCK / 64; ++w) s += ws[w];
        atomicAdd(out, s * (1.0f / (float)NTOT));
    }
}

extern "C" void kernel_launch(void* const* d_in, const int* in_sizes, int n_in,
                              void* d_out, int out_size, void* d_ws, size_t ws_size,
                              hipStream_t stream) {
    const float* img = (const float*)d_in[0];
    const int*   xA  = (const int*)d_in[1];
    const int*   yA  = (const int*)d_in[2];
    const int*   xB  = (const int*)d_in[3];
    const int*   yB  = (const int*)d_in[4];
    const int*   od  = (const int*)d_in[5];
    float* out = (float*)d_out;

    hipMemsetAsync(out, 0, sizeof(float), stream);
    rdl_kernel<<<NBLK, BLOCK, 0, stream>>>(img, xA, yA, xB, yB, od, out);
}